// Round 2
// baseline (2357.647 us; speedup 1.0000x reference)
//
#include <hip/hip_runtime.h>
#include <hip/hip_bf16.h>

// BitLinear: out[t,o] = sum_i x[t,i] * ternary(w)[o,i] + bias[o]
//   ternary(w) = sign(w) * (|w| >= 0.7*mean(|w|)),  {-1,0,1} exact in bf16.
// Pipeline: (1) |w| sum reduce (double), (2) quantize w -> bf16 ternary in ws,
//           (3) cast x -> bf16 in ws, (4) bf16 MFMA GEMM (m97 128x128 structure).

#define TOKENS 8192
#define INFEAT 4096
#define OUTFEAT 16384

typedef __bf16 bf16x8 __attribute__((ext_vector_type(8)));
typedef float f32x4 __attribute__((ext_vector_type(4)));
typedef unsigned short u16x8 __attribute__((ext_vector_type(8)));

__device__ __forceinline__ void gload_lds16(const void* g, void* l) {
    __builtin_amdgcn_global_load_lds(
        (const __attribute__((address_space(1))) void*)g,
        (__attribute__((address_space(3))) void*)l, 16, 0, 0);
}

// ---------------- pass 1: sum(|w|) in double ----------------
__global__ void k_abssum(const float* __restrict__ w, double* __restrict__ out) {
    const size_t n = (size_t)OUTFEAT * INFEAT;
    size_t idx = ((size_t)blockIdx.x * blockDim.x + threadIdx.x) * 4;
    const size_t stride = (size_t)gridDim.x * blockDim.x * 4;
    double acc = 0.0;
    for (size_t i = idx; i < n; i += stride) {
        float4 v = *reinterpret_cast<const float4*>(w + i);
        acc += (double)fabsf(v.x);
        acc += (double)fabsf(v.y);
        acc += (double)fabsf(v.z);
        acc += (double)fabsf(v.w);
    }
    // wave reduce (64 lanes)
    for (int off = 32; off > 0; off >>= 1) acc += __shfl_down(acc, off);
    __shared__ double part[4];
    int lane = threadIdx.x & 63, wid = threadIdx.x >> 6;
    if (lane == 0) part[wid] = acc;
    __syncthreads();
    if (threadIdx.x == 0) {
        atomicAdd(out, part[0] + part[1] + part[2] + part[3]);
    }
}

// ---------------- pass 2: quantize w -> ternary bf16 ----------------
__global__ void k_quant_w(const float* __restrict__ w, const double* __restrict__ sum,
                          unsigned short* __restrict__ wq) {
    const float scale = (float)(*sum * (1.0 / ((double)OUTFEAT * (double)INFEAT)));
    const float thr = scale * 0.7f;
    const size_t n = (size_t)OUTFEAT * INFEAT;
    size_t idx = ((size_t)blockIdx.x * blockDim.x + threadIdx.x) * 8;
    const size_t stride = (size_t)gridDim.x * blockDim.x * 8;
    for (size_t i = idx; i < n; i += stride) {
        float4 a = *reinterpret_cast<const float4*>(w + i);
        float4 b = *reinterpret_cast<const float4*>(w + i + 4);
        float v[8] = {a.x, a.y, a.z, a.w, b.x, b.y, b.z, b.w};
        u16x8 q;
#pragma unroll
        for (int j = 0; j < 8; ++j) {
            // bf16 bits: +1 = 0x3F80, -1 = 0xBF80, 0 = 0x0000
            q[j] = (fabsf(v[j]) >= thr) ? (v[j] > 0.0f ? 0x3F80u : 0xBF80u) : 0u;
        }
        *reinterpret_cast<u16x8*>(wq + i) = q;
    }
}

// ---------------- pass 3: cast x -> bf16 ----------------
__global__ void k_cast_x(const float* __restrict__ x, unsigned short* __restrict__ xb) {
    const size_t n = (size_t)TOKENS * INFEAT;
    size_t idx = ((size_t)blockIdx.x * blockDim.x + threadIdx.x) * 8;
    const size_t stride = (size_t)gridDim.x * blockDim.x * 8;
    for (size_t i = idx; i < n; i += stride) {
        float4 a = *reinterpret_cast<const float4*>(x + i);
        float4 b = *reinterpret_cast<const float4*>(x + i + 4);
        float v[8] = {a.x, a.y, a.z, a.w, b.x, b.y, b.z, b.w};
        u16x8 q;
#pragma unroll
        for (int j = 0; j < 8; ++j) {
            __hip_bfloat16 h = __float2bfloat16(v[j]);  // RNE
            q[j] = *reinterpret_cast<unsigned short*>(&h);
        }
        *reinterpret_cast<u16x8*>(xb + i) = q;
    }
}

// ---------------- pass 4: bf16 GEMM, C = A @ B^T + bias ----------------
// A: [M][K] bf16 (x), B: [N][K] bf16 (w_q, row-major K-contig = B^T layout),
// C: [M][N] fp32. m97 structure: 128x128 tile, BK=32, 256 thr = 4 waves,
// each wave computes a 64x64 sub-tile as 4x4 of 16x16x32 MFMA fragments.
__global__ __launch_bounds__(256) void k_gemm(
    const unsigned short* __restrict__ A, const unsigned short* __restrict__ B,
    const float* __restrict__ bias, float* __restrict__ C) {
    constexpr int M = TOKENS, N = OUTFEAT, K = INFEAT;
    constexpr int BM = 128, BN = 128, BK = 32;
    __shared__ __align__(16) unsigned short As[BM * BK];
    __shared__ __align__(16) unsigned short Bs[BN * BK];

    // XCD-bijective swizzle (nwg = 8192, divisible by 8)
    const int nwg = gridDim.x;
    const int per = nwg >> 3;
    const int bid = blockIdx.x;
    const int wg = (bid & 7) * per + (bid >> 3);
    constexpr int ntn = N / BN;  // 128
    const int tm = wg / ntn, tn = wg % ntn;
    const size_t brow = (size_t)tm * BM, bcol = (size_t)tn * BN;

    const int tid = threadIdx.x;
    const int lane = tid & 63, wid = tid >> 6;
    const int wr = (wid >> 1) * 64, wc = (wid & 1) * 64;
    const int fr = lane & 15, fq = lane >> 4;

    f32x4 acc[4][4] = {};

    // staging: lane -> (row = tid/4, 16B chunk = tid%4); LDS dest = base + tid*16B
    const int sr = tid >> 2;
    const int sc = (tid & 3) * 8;
    const unsigned short* ga = A + (brow + sr) * (size_t)K + sc;
    const unsigned short* gb = B + (bcol + sr) * (size_t)K + sc;

    for (int kt = 0; kt < K; kt += BK) {
        gload_lds16(ga, &As[sr * BK + sc]);
        gload_lds16(ga + (size_t)64 * K, &As[(sr + 64) * BK + sc]);
        gload_lds16(gb, &Bs[sr * BK + sc]);
        gload_lds16(gb + (size_t)64 * K, &Bs[(sr + 64) * BK + sc]);
        ga += BK;
        gb += BK;
        __syncthreads();  // drains vmcnt before barrier (compiler-enforced)

        bf16x8 a[4], b[4];
#pragma unroll
        for (int m = 0; m < 4; ++m)
            a[m] = *reinterpret_cast<const bf16x8*>(&As[(wr + m * 16 + fr) * BK + fq * 8]);
#pragma unroll
        for (int n = 0; n < 4; ++n)
            b[n] = *reinterpret_cast<const bf16x8*>(&Bs[(wc + n * 16 + fr) * BK + fq * 8]);
#pragma unroll
        for (int m = 0; m < 4; ++m)
#pragma unroll
            for (int n = 0; n < 4; ++n)
                acc[m][n] = __builtin_amdgcn_mfma_f32_16x16x32_bf16(a[m], b[n], acc[m][n], 0, 0, 0);
        __syncthreads();
    }

    // epilogue: C/D layout col = lane&15, row = (lane>>4)*4 + j   [m89/m91]
#pragma unroll
    for (int n = 0; n < 4; ++n) {
        const size_t col = bcol + wc + n * 16 + fr;
        const float bv = bias[col];
#pragma unroll
        for (int m = 0; m < 4; ++m) {
            const size_t row0 = brow + wr + m * 16 + fq * 4;
#pragma unroll
            for (int j = 0; j < 4; ++j)
                C[(row0 + j) * (size_t)N + col] = acc[m][n][j] + bv;
        }
    }
}

extern "C" void kernel_launch(void* const* d_in, const int* in_sizes, int n_in,
                              void* d_out, int out_size, void* d_ws, size_t ws_size,
                              hipStream_t stream) {
    const float* x = (const float*)d_in[0];     // [8192, 4096]
    const float* w = (const float*)d_in[1];     // [16384, 4096]
    const float* bias = (const float*)d_in[2];  // [16384]
    float* out = (float*)d_out;                 // [8192, 16384] fp32

    // ws layout: [0,8) double sum; [256, +128MB) w_q bf16; then x bf16 (64MB)
    double* sum = (double*)d_ws;
    unsigned short* wq = (unsigned short*)((char*)d_ws + 256);
    unsigned short* xb = (unsigned short*)((char*)d_ws + 256 + (size_t)OUTFEAT * INFEAT * 2);

    hipMemsetAsync(d_ws, 0, 8, stream);
    k_abssum<<<2048, 256, 0, stream>>>(w, sum);
    k_quant_w<<<2048, 256, 0, stream>>>(w, sum, wq);
    k_cast_x<<<2048, 256, 0, stream>>>(x, xb);

    constexpr int grid = (TOKENS / 128) * (OUTFEAT / 128);  // 8192
    k_gemm<<<grid, 256, 0, stream>>>(xb, wq, bias, out);
}